// Round 9
// baseline (2471.944 us; speedup 1.0000x reference)
//
#include <hip/hip_runtime.h>
#include <hip/hip_bf16.h>

// PointSpatialConv: FPS + ball-query grouping + 2x (1x1 conv + BN + ReLU) + max over K.
// B=2, T=8, N=4096, M=1024, K=32, C1=64, C2=128.
//
// Round 9: (1) fps: winner coords broadcast via per-wave scand slots written
// pre-barrier from registers -> post-barrier is ONE parallel LDS read batch
// (slot + 8 candidates) + cndmask select, replacing the dependent
// slot-read -> coord-read chain (~250cy -> ~160cy).
// (2) gram_mfma: 256-sample staging rounds (all threads), 24 barriers vs 128.
// Pipeline: memset, fps, ball_stats, gram_mfma, fold2, final_mfma.

#define N_PTS   4096
#define M_PTS   1024
#define KNB     32

typedef _Float16 half8 __attribute__((ext_vector_type(8)));
typedef float    f32x4 __attribute__((ext_vector_type(4)));

// packed f32 helpers (exact IEEE per-half, no contraction)
__device__ inline float2 pk_sub(float2 a, float2 b) {
  float2 d;
  asm("v_pk_add_f32 %0, %1, %2 neg_lo:[0,1] neg_hi:[0,1]" : "=v"(d) : "v"(a), "v"(b));
  return d;
}
__device__ inline float2 pk_mul(float2 a, float2 b) {
  float2 d;
  asm("v_pk_mul_f32 %0, %1, %2" : "=v"(d) : "v"(a), "v"(b));
  return d;
}
__device__ inline float2 pk_add(float2 a, float2 b) {
  float2 d;
  asm("v_pk_add_f32 %0, %1, %2" : "=v"(d) : "v"(a), "v"(b));
  return d;
}

// f32 DPP max step: shifted-in lanes get 0.0 (identity for dd >= 0)
#define DPPMAXF(ctrl)                                                          \
  {                                                                            \
    unsigned _o = (unsigned)__builtin_amdgcn_update_dpp(                       \
        0, (int)__float_as_uint(m), (ctrl), 0xF, 0xF, true);                   \
    m = fmaxf(m, __uint_as_float(_o));                                         \
  }

// inline BN1-fold: per-channel folded W1 row
__device__ inline float4 fold1_chan(const float* __restrict__ acc9, int t, int c,
                                    const float* __restrict__ W1,
                                    const float* __restrict__ g1,
                                    const float* __restrict__ b1) {
  const float inv_n = 1.0f / 65536.0f;
  const float* a = acc9 + t * 9;
  float mx = a[0] * inv_n, my = a[1] * inv_n, mz = a[2] * inv_n;
  float Sxx = a[3] * inv_n, Syy = a[4] * inv_n, Szz = a[5] * inv_n;
  float Sxy = a[6] * inv_n, Sxz = a[7] * inv_n, Syz = a[8] * inv_n;
  float w0 = W1[c * 4], w1 = W1[c * 4 + 1], w2 = W1[c * 4 + 2];
  float mean = w0 * mx + w1 * my + w2 * mz;
  float E2 = w0 * w0 * Sxx + w1 * w1 * Syy + w2 * w2 * Szz
           + 2.f * (w0 * w1 * Sxy + w0 * w2 * Sxz + w1 * w2 * Syz);
  float var = E2 - mean * mean;
  float al = g1[c] / sqrtf(var + 1e-5f);
  float4 o; o.x = w0 * al; o.y = w1 * al; o.z = w2 * al; o.w = b1[c] - mean * al;
  return o;
}

// ---------------------------------------------------------------- FPS
__global__ __launch_bounds__(512) void fps_kernel(const float* __restrict__ xyzs,
                                                  float* __restrict__ out) {
#pragma clang fp contract(off)
  const int bt  = blockIdx.x & 15;
  const int tid = threadIdx.x;
  __shared__ float sx[N_PTS], syy[N_PTS], szz[N_PTS];
  __shared__ unsigned long long sslot[2];   // it-tagged keys: no reset needed
  __shared__ float4 scand[2][8];            // per-wave candidate coords, dbuf
  __shared__ int sidx[M_PTS];

  const float* f = xyzs + (size_t)bt * (N_PTS * 3);
  for (int i = tid; i < N_PTS; i += 512) {
    sx[i]  = f[3 * i + 0];
    syy[i] = f[3 * i + 1];
    szz[i] = f[3 * i + 2];
  }
  if (tid == 0) { sidx[0] = 0; sslot[0] = 0ull; sslot[1] = 0ull; }
  __syncthreads();

  const int base = tid << 3;               // thread owns points [8*tid, 8*tid+8)
  float2 px2[4], py2[4], pz2[4], dd2[4];
#pragma unroll
  for (int j = 0; j < 4; ++j) {
    int i0 = base + 2 * j;
    px2[j] = {sx[i0], sx[i0 + 1]};
    py2[j] = {syy[i0], syy[i0 + 1]};
    pz2[j] = {szz[i0], szz[i0 + 1]};
    dd2[j] = {1e10f, 1e10f};
  }
  float wx = sx[0], wy = syy[0], wz = szz[0];

  for (int it = 1; it < M_PTS; ++it) {
    float2 wxx = {wx, wx}, wyy = {wy, wy}, wzz = {wz, wz};
#pragma unroll
    for (int j = 0; j < 4; ++j) {
      float2 dx = pk_sub(px2[j], wxx);
      float2 dy = pk_sub(py2[j], wyy);
      float2 dz = pk_sub(pz2[j], wzz);
      float2 m1 = pk_mul(dx, dx);
      float2 m2 = pk_mul(dy, dy);
      float2 s  = pk_add(m1, m2);
      float2 m3 = pk_mul(dz, dz);
      float2 dt = pk_add(s, m3);
      dd2[j].x = fminf(dd2[j].x, dt.x);
      dd2[j].y = fminf(dd2[j].y, dt.y);
    }
    // strict-> tree over 8 local values (challenger always higher index)
    float v4[4]; int s4[4];
#pragma unroll
    for (int a = 0; a < 4; ++a) {
      bool t = dd2[a].y > dd2[a].x;
      v4[a] = t ? dd2[a].y : dd2[a].x;
      s4[a] = 2 * a + (t ? 1 : 0);
    }
    float v2[2]; int s2v[2];
#pragma unroll
    for (int a = 0; a < 2; ++a) {
      bool t = v4[2 * a + 1] > v4[2 * a];
      v2[a] = t ? v4[2 * a + 1] : v4[2 * a];
      s2v[a] = t ? s4[2 * a + 1] : s4[2 * a];
    }
    bool t1 = v2[1] > v2[0];
    float bv = t1 ? v2[1] : v2[0];
    int   bj = t1 ? s2v[1] : s2v[0];

    // wave max on VALUE only (f32 DPP chain, result in lane 63)
    float m = bv;
    DPPMAXF(0x111);  // row_shr:1
    DPPMAXF(0x112);  // row_shr:2
    DPPMAXF(0x114);  // row_shr:4
    DPPMAXF(0x118);  // row_shr:8
    DPPMAXF(0x142);  // row_bcast:15
    DPPMAXF(0x143);  // row_bcast:31
    float vmax = __uint_as_float(
        (unsigned)__builtin_amdgcn_readlane((int)__float_as_uint(m), 63));

    // wave's first matching lane (= min gi in wave, consecutive layout):
    // writes its candidate coords from REGISTERS + submits the key.
    unsigned long long mk = __ballot(bv == vmax);
    const int p = it & 1;
    if ((tid & 63) == (int)__builtin_ctzll(mk)) {
      float2 ax = (bj & 4) ? ((bj & 2) ? px2[3] : px2[2])
                           : ((bj & 2) ? px2[1] : px2[0]);
      float2 ay = (bj & 4) ? ((bj & 2) ? py2[3] : py2[2])
                           : ((bj & 2) ? py2[1] : py2[0]);
      float2 az = (bj & 4) ? ((bj & 2) ? pz2[3] : pz2[2])
                           : ((bj & 2) ? pz2[1] : pz2[0]);
      float4 cc;
      cc.x = (bj & 1) ? ax.y : ax.x;
      cc.y = (bj & 1) ? ay.y : ay.x;
      cc.z = (bj & 1) ? az.y : az.x;
      cc.w = 0.f;
      scand[p][tid >> 6] = cc;
      unsigned gi = (unsigned)((tid << 3) + bj);
      unsigned long long key = ((unsigned long long)(unsigned)it << 44)
          | ((unsigned long long)__float_as_uint(bv) << 12)
          | (unsigned long long)(4095u - gi);
      atomicMax(&sslot[p], key);
    }
    __syncthreads();
    // one PARALLEL read batch: slot + all 8 candidates (no dependency),
    // then register select by winning wave id.
    float4 c0 = scand[p][0], c1 = scand[p][1], c2 = scand[p][2], c3 = scand[p][3];
    float4 c4 = scand[p][4], c5 = scand[p][5], c6 = scand[p][6], c7 = scand[p][7];
    unsigned long long kk = sslot[p];
    int gi_w = 4095 - (int)(kk & 0xFFFull);
    int wv = gi_w >> 9;                    // winning wave 0..7
    float4 a0 = (wv & 1) ? c1 : c0;
    float4 a1 = (wv & 1) ? c3 : c2;
    float4 a2 = (wv & 1) ? c5 : c4;
    float4 a3 = (wv & 1) ? c7 : c6;
    float4 b0 = (wv & 2) ? a1 : a0;
    float4 b1 = (wv & 2) ? a3 : a2;
    float4 cw = (wv & 4) ? b1 : b0;
    wx = cw.x; wy = cw.y; wz = cw.z;
    if (tid == 0) sidx[it] = gi_w;
  }
  __syncthreads();
  float* orow = out + (size_t)bt * (M_PTS * 3);
  for (int i = tid; i < M_PTS; i += 512) {
    int ix = sidx[i];
    orow[3 * i + 0] = sx[ix];
    orow[3 * i + 1] = syy[ix];
    orow[3 * i + 2] = szz[ix];
  }
}

// ---------------------------------------------------------------- ball query + BN1 moments
__global__ __launch_bounds__(256) void ball_stats(const float* __restrict__ xyzs,
                                                  const float* __restrict__ refpts,
                                                  float* __restrict__ disp4,
                                                  float* __restrict__ acc9) {
#pragma clang fp contract(off)
  const int tid  = threadIdx.x;
  const int lane = tid & 63, w = tid >> 6;
  const int gw   = (blockIdx.x << 2) + w;      // ref point id, 0..16383
  const int bt   = gw >> 10;
  const float* f = xyzs + (size_t)bt * (N_PTS * 3);
  const float* r = refpts + (size_t)gw * 3;
  const float rx = r[0], ry = r[1], rz = r[2];
  float* dout = disp4 + (size_t)gw * (KNB * 4);
  __shared__ float sred[4][9];

  float st[9];
#pragma unroll
  for (int q = 0; q < 9; ++q) st[q] = 0.f;

  int filled = 0;
  float p0x = 0.f, p0y = 0.f, p0z = 0.f;
  bool got0 = false;

  for (int base = 0; base < N_PTS; base += 64) {
    if (filled >= KNB) break;
    int j = base + lane;
    float x = f[3 * j], y = f[3 * j + 1], z = f[3 * j + 2];
    float dx = rx - x, dy = ry - y, dz = rz - z;
    float d2 = (dx * dx + dy * dy) + dz * dz;    // exact numpy order
    bool pred = d2 < 0.81f;
    unsigned long long mk = __ballot(pred);
    if (!got0 && mk) {
      int src = __builtin_ctzll(mk);
      p0x = __shfl(-dx, src); p0y = __shfl(-dy, src); p0z = __shfl(-dz, src);
      got0 = true;
    }
    int slot = filled + __popcll(mk & ((1ull << lane) - 1));
    if (pred && slot < KNB) {
      float vx = -dx, vy = -dy, vz = -dz;
      float4 v; v.x = vx; v.y = vy; v.z = vz; v.w = 0.f;
      *(float4*)(dout + slot * 4) = v;
      st[0] += vx;      st[1] += vy;      st[2] += vz;
      st[3] += vx * vx; st[4] += vy * vy; st[5] += vz * vz;
      st[6] += vx * vy; st[7] += vx * vz; st[8] += vy * vz;
    }
    filled += __popcll(mk);
  }
  if (filled < KNB) {                            // pad with first neighbor
    for (int s = filled + lane; s < KNB; s += 64) {
      float4 v; v.x = p0x; v.y = p0y; v.z = p0z; v.w = 0.f;
      *(float4*)(dout + s * 4) = v;
    }
    if (lane == 0) {
      float cf = (float)(KNB - filled);
      st[0] += cf * p0x;       st[1] += cf * p0y;       st[2] += cf * p0z;
      st[3] += cf * p0x * p0x; st[4] += cf * p0y * p0y; st[5] += cf * p0z * p0z;
      st[6] += cf * p0x * p0y; st[7] += cf * p0x * p0z; st[8] += cf * p0y * p0z;
    }
  }
#pragma unroll
  for (int q = 0; q < 9; ++q) {
#pragma unroll
    for (int off = 1; off < 64; off <<= 1) st[q] += __shfl_xor(st[q], off);
  }
  if (lane == 0) {
#pragma unroll
    for (int q = 0; q < 9; ++q) sred[w][q] = st[q];
  }
  __syncthreads();
  if (tid < 9) {
    float v = sred[0][tid] + sred[1][tid] + sred[2][tid] + sred[3][tid];
    atomicAdd(&acc9[(bt & 7) * 9 + tid], v);
  }
}

// ---------------------------------------------------------------- Gram via f16 MFMA
// yt[64 c][256 s] f16 (32 KB), 16B-granule swizzle g ^= (row&7) both sides.
// 8 staging rounds of 256 samples (all threads), 8 MFMA sub-tiles per round.
__global__ __launch_bounds__(256) void gram_mfma(
    const float* __restrict__ disp4, const float* __restrict__ acc9,
    const float* __restrict__ W1, const float* __restrict__ g1,
    const float* __restrict__ b1,
    float* __restrict__ sumy, float* __restrict__ G) {
  const int t = blockIdx.x >> 5, chunk = blockIdx.x & 31;
  const int tid = threadIdx.x;
  const int lane = tid & 63, w = tid >> 6;
  __shared__ float4    sdisp[256];        // 4 KB
  __shared__ _Float16  yt[64 * 256];      // 32 KB, row stride 512B
  __shared__ float     red[256];

  const int c = lane;
  float4 wc = fold1_chan(acc9, t, c, W1, g1, b1);
  f32x4 g0 = {0.f,0.f,0.f,0.f}, g1a = {0.f,0.f,0.f,0.f};
  f32x4 g2a = {0.f,0.f,0.f,0.f}, g3 = {0.f,0.f,0.f,0.f};
  float ysum = 0.f;
  const int frc = lane & 15, kg = lane >> 4;
  const int fsw = frc & 7;                // read-side row swizzle (row&7, rows≡frc mod 8)

  for (int rnd = 0; rnd < 8; ++rnd) {
    int smp = (chunk << 11) + (rnd << 8) + tid;
    size_t flat = ((size_t)(smp >> 15) << 18) + ((size_t)t << 15) + (smp & 32767);
    sdisp[tid] = ((const float4*)disp4)[flat];
    __syncthreads();
    // y1: thread does c=lane, samples [w*64, w*64+64)
    char* rowb = (char*)yt + c * 512;
    const int cs = c & 7;
#pragma unroll
    for (int u8 = 0; u8 < 8; ++u8) {
      half8 hv;
#pragma unroll
      for (int u = 0; u < 8; ++u) {
        float4 d = sdisp[(w << 6) + (u8 << 3) + u];
        float y = wc.x * d.x + wc.y * d.y + wc.z * d.z + wc.w;
        y = y > 0.f ? y : 0.f;
        ysum += y;
        hv[u] = (_Float16)y;
      }
      int g = (w << 3) + u8;              // granule 0..31 in row
      *(half8*)(rowb + (((g ^ cs)) << 4)) = hv;
    }
    __syncthreads();
#pragma unroll
    for (int ss = 0; ss < 8; ++ss) {
      int gg = (ss << 2) + kg;
      half8 fA = *(const half8*)((char*)yt + ((16 * w + frc) << 9) + ((gg ^ fsw) << 4));
      half8 f0 = *(const half8*)((char*)yt + ((frc) << 9)          + ((gg ^ fsw) << 4));
      half8 f1 = *(const half8*)((char*)yt + ((16 + frc) << 9)     + ((gg ^ fsw) << 4));
      half8 f2 = *(const half8*)((char*)yt + ((32 + frc) << 9)     + ((gg ^ fsw) << 4));
      half8 f3 = *(const half8*)((char*)yt + ((48 + frc) << 9)     + ((gg ^ fsw) << 4));
      g0  = __builtin_amdgcn_mfma_f32_16x16x32_f16(fA, f0, g0, 0, 0, 0);
      g1a = __builtin_amdgcn_mfma_f32_16x16x32_f16(fA, f1, g1a, 0, 0, 0);
      g2a = __builtin_amdgcn_mfma_f32_16x16x32_f16(fA, f2, g2a, 0, 0, 0);
      g3  = __builtin_amdgcn_mfma_f32_16x16x32_f16(fA, f3, g3, 0, 0, 0);
    }
    __syncthreads();
  }
  red[tid] = ysum;
  __syncthreads();
  if (tid < 64) {
    float v = red[tid] + red[tid + 64] + red[tid + 128] + red[tid + 192];
    atomicAdd(&sumy[t * 64 + tid], v);
  }
  float* Gp = G + t * 4096;
  const int rbase = 16 * w + (lane >> 4) * 4, cb = lane & 15;
#pragma unroll
  for (int r2 = 0; r2 < 4; ++r2) {
    atomicAdd(&Gp[(rbase + r2) * 64 + cb],      g0[r2]);
    atomicAdd(&Gp[(rbase + r2) * 64 + 16 + cb], g1a[r2]);
    atomicAdd(&Gp[(rbase + r2) * 64 + 32 + cb], g2a[r2]);
    atomicAdd(&Gp[(rbase + r2) * 64 + 48 + cb], g3[r2]);
  }
}

// ---------------------------------------------------------------- BN2 fold -> f16 W2'
__global__ __launch_bounds__(256) void fold2_kernel(const float* __restrict__ G,
    const float* __restrict__ sumy, const float* __restrict__ W2,
    const float* __restrict__ g2, const float* __restrict__ b2,
    _Float16* __restrict__ w2ph, float* __restrict__ beta2) {
  const int gidx = blockIdx.x * 256 + threadIdx.x;  // 0..1023
  const int t = gidx >> 7, c2 = gidx & 127;
  const float inv_n = 1.f / 65536.f;
  const float* w = W2 + c2 * 64;
  float wreg[64];
#pragma unroll
  for (int q = 0; q < 16; ++q) {
    float4 v = ((const float4*)w)[q];
    wreg[4 * q] = v.x; wreg[4 * q + 1] = v.y; wreg[4 * q + 2] = v.z; wreg[4 * q + 3] = v.w;
  }
  float mean2 = 0.f;
#pragma unroll
  for (int j = 0; j < 64; ++j) mean2 += wreg[j] * (sumy[t * 64 + j] * inv_n);
  const float* Gp = G + t * 4096;
  float E2 = 0.f;
  for (int i = 0; i < 64; ++i) {
    const float* gr = Gp + i * 64;
    float gw = 0.f;
#pragma unroll
    for (int j = 0; j < 64; j += 4) {
      float4 gv = *(const float4*)&gr[j];
      gw += gv.x * wreg[j] + gv.y * wreg[j + 1] + gv.z * wreg[j + 2] + gv.w * wreg[j + 3];
    }
    E2 += wreg[i] * gw;
  }
  E2 *= inv_n;
  float var = E2 - mean2 * mean2;
  float al = g2[c2] / sqrtf(var + 1e-5f);
  float be = b2[c2] - mean2 * al;
  beta2[t * 128 + c2] = be;
  _Float16* wo = w2ph + (size_t)(t * 128 + c2) * 64;
#pragma unroll
  for (int j = 0; j < 64; ++j) wo[j] = (_Float16)(al * wreg[j]);
}

// ---------------------------------------------------------------- final: f16 MFMA GEMM + k-max
__global__ __launch_bounds__(256) void final_mfma(
    const float* __restrict__ disp4, const float* __restrict__ acc9,
    const float* __restrict__ W1, const float* __restrict__ g1,
    const float* __restrict__ b1,
    const _Float16* __restrict__ w2ph, const float* __restrict__ beta2,
    float* __restrict__ outfeat) {
  const int bid = blockIdx.x;          // 1024 = bt(16) x mgrp(64)
  const int bt = bid >> 6, mg = bid & 63;
  const int t = bt & 7;
  const int tid = threadIdx.x;
  const int lane = tid & 63, w = tid >> 6;

  __shared__ float4    sdisp[512];     // 16 m x 32 k (8 KB)
  __shared__ _Float16  sy[512 * 64];   // swizzled y1 (64 KB)

  {
    const float4* src = (const float4*)disp4 + (((size_t)(bt << 10) + (mg << 4)) << 5);
    sdisp[tid] = src[tid];
    sdisp[tid + 256] = src[tid + 256];
  }
  const int c0 = (tid & 31) * 2;
  float4 w1a = fold1_chan(acc9, t, c0, W1, g1, b1);
  float4 w1b = fold1_chan(acc9, t, c0 + 1, W1, g1, b1);
  __syncthreads();

  {
    const int r0 = (tid >> 5) * 64;
    const int hg = c0 >> 3;
    const int cin = (c0 & 7) * 2;
#pragma unroll 4
    for (int rr = 0; rr < 64; ++rr) {
      int row = r0 + rr;
      float4 d = sdisp[row];
      float ya = fmaxf(w1a.x * d.x + w1a.y * d.y + w1a.z * d.z + w1a.w, 0.f);
      float yb = fmaxf(w1b.x * d.x + w1b.y * d.y + w1b.z * d.z + w1b.w, 0.f);
      _Float16* p = (_Float16*)((char*)sy + row * 128 + ((hg ^ (row & 7)) * 16) + cin);
      p[0] = (_Float16)ya;
      p[1] = (_Float16)yb;
    }
  }
  __syncthreads();

  const int col = lane & 15, kg = lane >> 4;
  for (int ct = 0; ct < 8; ++ct) {
    const _Float16* wb = w2ph + ((size_t)(t * 128 + ct * 16 + col)) * 64 + kg * 8;
    half8 bf0 = *(const half8*)wb;
    half8 bf1 = *(const half8*)(wb + 32);
    float b2v = beta2[t * 128 + ct * 16 + col];
#pragma unroll
    for (int mi = 0; mi < 4; ++mi) {
      float mx = -1e30f;
#pragma unroll
      for (int h = 0; h < 2; ++h) {
        int row = (8 * w + 2 * mi + h) * 16 + col;
        int rm = row & 7;
        const char* rb = (const char*)sy + row * 128;
        half8 a0 = *(const half8*)(rb + ((kg ^ rm) * 16));
        half8 a1 = *(const half8*)(rb + (((4 + kg) ^ rm) * 16));
        f32x4 acc = {0.f, 0.f, 0.f, 0.f};
        acc = __builtin_amdgcn_mfma_f32_16x16x32_f16(a0, bf0, acc, 0, 0, 0);
        acc = __builtin_amdgcn_mfma_f32_16x16x32_f16(a1, bf1, acc, 0, 0, 0);
        float z = fmaxf(fmaxf(acc[0], acc[1]), fmaxf(acc[2], acc[3]));
        mx = fmaxf(mx, z);
      }
      mx = fmaxf(mx, __shfl_xor(mx, 16));
      mx = fmaxf(mx, __shfl_xor(mx, 32));
      if (lane < 16) {
        float v = fmaxf(mx + b2v, 0.f);
        int m = (mg << 4) + 4 * w + mi;
        outfeat[((size_t)(bt * 128 + ct * 16 + lane)) * 1024 + m] = v;
      }
    }
  }
}

// ---------------------------------------------------------------- launch
extern "C" void kernel_launch(void* const* d_in, const int* in_sizes, int n_in,
                              void* d_out, int out_size, void* d_ws, size_t ws_size,
                              hipStream_t stream) {
  const float* xyzs = (const float*)d_in[0];
  const float* W1   = (const float*)d_in[1];
  const float* g1   = (const float*)d_in[2];
  const float* b1   = (const float*)d_in[3];
  const float* W2   = (const float*)d_in[4];
  const float* g2   = (const float*)d_in[5];
  const float* b2   = (const float*)d_in[6];
  float* out = (float*)d_out;
  float* ws  = (float*)d_ws;

  float*     disp4 = ws;               // 2,097,152 floats (B,T,M,K,4)
  float*     acc   = ws + 2097152;     // 72
  float*     sumy  = ws + 2097224;     // 512
  float*     G     = ws + 2097736;     // 32768 (acc..G contiguous for one memset)
  _Float16*  w2ph  = (_Float16*)(ws + 2130504);  // 65536 halves
  float*     beta2 = ws + 2163272;     // 1024

  hipMemsetAsync(acc, 0, (72 + 512 + 32768) * sizeof(float), stream);
  fps_kernel  <<<256,  512, 0, stream>>>(xyzs, out);
  ball_stats  <<<4096, 256, 0, stream>>>(xyzs, out, disp4, acc);
  gram_mfma   <<<256,  256, 0, stream>>>(disp4, acc, W1, g1, b1, sumy, G);
  fold2_kernel<<<4,    256, 0, stream>>>(G, sumy, W2, g2, b2, w2ph, beta2);
  final_mfma  <<<1024, 256, 0, stream>>>(disp4, acc, W1, g1, b1, w2ph, beta2, out + 49152);
}

// Round 10
// 977.113 us; speedup vs baseline: 2.5298x; 2.5298x over previous
//
#include <hip/hip_runtime.h>
#include <hip/hip_bf16.h>

// PointSpatialConv: FPS + ball-query grouping + 2x (1x1 conv + BN + ReLU) + max over K.
// B=2, T=8, N=4096, M=1024, K=32, C1=64, C2=128.
//
// Round 10: recombine proven-best pieces. fps = round-8 version EXACTLY
// (758us; round-9's 8-float4 parallel read caused register spills: WRITE_SIZE
// 192KB->12.5MB, fps 758->2322). Rest = round-9 (gram 256-sample restage cut
// "others" 238->150us). Pipeline: memset, fps, ball_stats, gram_mfma, fold2,
// final_mfma.

#define N_PTS   4096
#define M_PTS   1024
#define KNB     32

typedef _Float16 half8 __attribute__((ext_vector_type(8)));
typedef float    f32x4 __attribute__((ext_vector_type(4)));

// packed f32 helpers (exact IEEE per-half, no contraction)
__device__ inline float2 pk_sub(float2 a, float2 b) {
  float2 d;
  asm("v_pk_add_f32 %0, %1, %2 neg_lo:[0,1] neg_hi:[0,1]" : "=v"(d) : "v"(a), "v"(b));
  return d;
}
__device__ inline float2 pk_mul(float2 a, float2 b) {
  float2 d;
  asm("v_pk_mul_f32 %0, %1, %2" : "=v"(d) : "v"(a), "v"(b));
  return d;
}
__device__ inline float2 pk_add(float2 a, float2 b) {
  float2 d;
  asm("v_pk_add_f32 %0, %1, %2" : "=v"(d) : "v"(a), "v"(b));
  return d;
}

// f32 DPP max step: shifted-in lanes get 0.0 (identity for dd >= 0)
#define DPPMAXF(ctrl)                                                          \
  {                                                                            \
    unsigned _o = (unsigned)__builtin_amdgcn_update_dpp(                       \
        0, (int)__float_as_uint(m), (ctrl), 0xF, 0xF, true);                   \
    m = fmaxf(m, __uint_as_float(_o));                                         \
  }

// inline BN1-fold: per-channel folded W1 row
__device__ inline float4 fold1_chan(const float* __restrict__ acc9, int t, int c,
                                    const float* __restrict__ W1,
                                    const float* __restrict__ g1,
                                    const float* __restrict__ b1) {
  const float inv_n = 1.0f / 65536.0f;
  const float* a = acc9 + t * 9;
  float mx = a[0] * inv_n, my = a[1] * inv_n, mz = a[2] * inv_n;
  float Sxx = a[3] * inv_n, Syy = a[4] * inv_n, Szz = a[5] * inv_n;
  float Sxy = a[6] * inv_n, Sxz = a[7] * inv_n, Syz = a[8] * inv_n;
  float w0 = W1[c * 4], w1 = W1[c * 4 + 1], w2 = W1[c * 4 + 2];
  float mean = w0 * mx + w1 * my + w2 * mz;
  float E2 = w0 * w0 * Sxx + w1 * w1 * Syy + w2 * w2 * Szz
           + 2.f * (w0 * w1 * Sxy + w0 * w2 * Sxz + w1 * w2 * Syz);
  float var = E2 - mean * mean;
  float al = g1[c] / sqrtf(var + 1e-5f);
  float4 o; o.x = w0 * al; o.y = w1 * al; o.z = w2 * al; o.w = b1[c] - mean * al;
  return o;
}

// ---------------------------------------------------------------- FPS (round-8, proven 758us)
__global__ __launch_bounds__(512) void fps_kernel(const float* __restrict__ xyzs,
                                                  float* __restrict__ out) {
#pragma clang fp contract(off)
  const int bt  = blockIdx.x & 15;
  const int tid = threadIdx.x;
  __shared__ float sx[N_PTS], syy[N_PTS], szz[N_PTS];
  __shared__ unsigned long long sslot[2];   // it-tagged keys: no reset needed
  __shared__ int sidx[M_PTS];

  const float* f = xyzs + (size_t)bt * (N_PTS * 3);
  for (int i = tid; i < N_PTS; i += 512) {
    sx[i]  = f[3 * i + 0];
    syy[i] = f[3 * i + 1];
    szz[i] = f[3 * i + 2];
  }
  if (tid == 0) { sidx[0] = 0; sslot[0] = 0ull; sslot[1] = 0ull; }
  __syncthreads();

  const int base = tid << 3;               // thread owns points [8*tid, 8*tid+8)
  float2 px2[4], py2[4], pz2[4], dd2[4];
#pragma unroll
  for (int j = 0; j < 4; ++j) {
    int i0 = base + 2 * j;
    px2[j] = {sx[i0], sx[i0 + 1]};
    py2[j] = {syy[i0], syy[i0 + 1]};
    pz2[j] = {szz[i0], szz[i0 + 1]};
    dd2[j] = {1e10f, 1e10f};
  }
  float wx = sx[0], wy = syy[0], wz = szz[0];

  for (int it = 1; it < M_PTS; ++it) {
    float2 wxx = {wx, wx}, wyy = {wy, wy}, wzz = {wz, wz};
#pragma unroll
    for (int j = 0; j < 4; ++j) {
      float2 dx = pk_sub(px2[j], wxx);
      float2 dy = pk_sub(py2[j], wyy);
      float2 dz = pk_sub(pz2[j], wzz);
      float2 m1 = pk_mul(dx, dx);
      float2 m2 = pk_mul(dy, dy);
      float2 s  = pk_add(m1, m2);
      float2 m3 = pk_mul(dz, dz);
      float2 dt = pk_add(s, m3);
      dd2[j].x = fminf(dd2[j].x, dt.x);
      dd2[j].y = fminf(dd2[j].y, dt.y);
    }
    // strict-> tree over 8 local values (challenger always higher index)
    float v4[4]; int s4[4];
#pragma unroll
    for (int a = 0; a < 4; ++a) {
      bool t = dd2[a].y > dd2[a].x;
      v4[a] = t ? dd2[a].y : dd2[a].x;
      s4[a] = 2 * a + (t ? 1 : 0);
    }
    float v2[2]; int s2v[2];
#pragma unroll
    for (int a = 0; a < 2; ++a) {
      bool t = v4[2 * a + 1] > v4[2 * a];
      v2[a] = t ? v4[2 * a + 1] : v4[2 * a];
      s2v[a] = t ? s4[2 * a + 1] : s4[2 * a];
    }
    bool t1 = v2[1] > v2[0];
    float bv = t1 ? v2[1] : v2[0];
    int   bj = t1 ? s2v[1] : s2v[0];

    // wave max on VALUE only (f32 DPP chain, result in lane 63)
    float m = bv;
    DPPMAXF(0x111);  // row_shr:1
    DPPMAXF(0x112);  // row_shr:2
    DPPMAXF(0x114);  // row_shr:4
    DPPMAXF(0x118);  // row_shr:8
    DPPMAXF(0x142);  // row_bcast:15
    DPPMAXF(0x143);  // row_bcast:31
    float vmax = __uint_as_float(
        (unsigned)__builtin_amdgcn_readlane((int)__float_as_uint(m), 63));

    // cross-wave argmax: matching lanes submit their own gi; atomicMax picks
    // (max val, min gi). key = (it<<44)|(valbits<<12)|(4095-gi): stale keys
    // (smaller it) always lose -> no reset; dbuf slot kills the read race.
    const int p = it & 1;
    if (bv == vmax) {
      unsigned long long key = ((unsigned long long)(unsigned)it << 44)
          | ((unsigned long long)__float_as_uint(bv) << 12)
          | (unsigned long long)(4095u - (unsigned)((tid << 3) + bj));
      atomicMax(&sslot[p], key);
    }
    __syncthreads();
    unsigned long long kk = sslot[p];
    int bi = 4095 - (int)(kk & 0xFFFull);
    wx = sx[bi]; wy = syy[bi]; wz = szz[bi];
    if (tid == 0) sidx[it] = bi;
  }
  __syncthreads();
  float* orow = out + (size_t)bt * (M_PTS * 3);
  for (int i = tid; i < M_PTS; i += 512) {
    int ix = sidx[i];
    orow[3 * i + 0] = sx[ix];
    orow[3 * i + 1] = syy[ix];
    orow[3 * i + 2] = szz[ix];
  }
}

// ---------------------------------------------------------------- ball query + BN1 moments
__global__ __launch_bounds__(256) void ball_stats(const float* __restrict__ xyzs,
                                                  const float* __restrict__ refpts,
                                                  float* __restrict__ disp4,
                                                  float* __restrict__ acc9) {
#pragma clang fp contract(off)
  const int tid  = threadIdx.x;
  const int lane = tid & 63, w = tid >> 6;
  const int gw   = (blockIdx.x << 2) + w;      // ref point id, 0..16383
  const int bt   = gw >> 10;
  const float* f = xyzs + (size_t)bt * (N_PTS * 3);
  const float* r = refpts + (size_t)gw * 3;
  const float rx = r[0], ry = r[1], rz = r[2];
  float* dout = disp4 + (size_t)gw * (KNB * 4);
  __shared__ float sred[4][9];

  float st[9];
#pragma unroll
  for (int q = 0; q < 9; ++q) st[q] = 0.f;

  int filled = 0;
  float p0x = 0.f, p0y = 0.f, p0z = 0.f;
  bool got0 = false;

  for (int base = 0; base < N_PTS; base += 64) {
    if (filled >= KNB) break;
    int j = base + lane;
    float x = f[3 * j], y = f[3 * j + 1], z = f[3 * j + 2];
    float dx = rx - x, dy = ry - y, dz = rz - z;
    float d2 = (dx * dx + dy * dy) + dz * dz;    // exact numpy order
    bool pred = d2 < 0.81f;
    unsigned long long mk = __ballot(pred);
    if (!got0 && mk) {
      int src = __builtin_ctzll(mk);
      p0x = __shfl(-dx, src); p0y = __shfl(-dy, src); p0z = __shfl(-dz, src);
      got0 = true;
    }
    int slot = filled + __popcll(mk & ((1ull << lane) - 1));
    if (pred && slot < KNB) {
      float vx = -dx, vy = -dy, vz = -dz;
      float4 v; v.x = vx; v.y = vy; v.z = vz; v.w = 0.f;
      *(float4*)(dout + slot * 4) = v;
      st[0] += vx;      st[1] += vy;      st[2] += vz;
      st[3] += vx * vx; st[4] += vy * vy; st[5] += vz * vz;
      st[6] += vx * vy; st[7] += vx * vz; st[8] += vy * vz;
    }
    filled += __popcll(mk);
  }
  if (filled < KNB) {                            // pad with first neighbor
    for (int s = filled + lane; s < KNB; s += 64) {
      float4 v; v.x = p0x; v.y = p0y; v.z = p0z; v.w = 0.f;
      *(float4*)(dout + s * 4) = v;
    }
    if (lane == 0) {
      float cf = (float)(KNB - filled);
      st[0] += cf * p0x;       st[1] += cf * p0y;       st[2] += cf * p0z;
      st[3] += cf * p0x * p0x; st[4] += cf * p0y * p0y; st[5] += cf * p0z * p0z;
      st[6] += cf * p0x * p0y; st[7] += cf * p0x * p0z; st[8] += cf * p0y * p0z;
    }
  }
#pragma unroll
  for (int q = 0; q < 9; ++q) {
#pragma unroll
    for (int off = 1; off < 64; off <<= 1) st[q] += __shfl_xor(st[q], off);
  }
  if (lane == 0) {
#pragma unroll
    for (int q = 0; q < 9; ++q) sred[w][q] = st[q];
  }
  __syncthreads();
  if (tid < 9) {
    float v = sred[0][tid] + sred[1][tid] + sred[2][tid] + sred[3][tid];
    atomicAdd(&acc9[(bt & 7) * 9 + tid], v);
  }
}

// ---------------------------------------------------------------- Gram via f16 MFMA
// yt[64 c][256 s] f16 (32 KB), 16B-granule swizzle g ^= (row&7) both sides.
// 8 staging rounds of 256 samples (all threads), 8 MFMA sub-tiles per round.
__global__ __launch_bounds__(256) void gram_mfma(
    const float* __restrict__ disp4, const float* __restrict__ acc9,
    const float* __restrict__ W1, const float* __restrict__ g1,
    const float* __restrict__ b1,
    float* __restrict__ sumy, float* __restrict__ G) {
  const int t = blockIdx.x >> 5, chunk = blockIdx.x & 31;
  const int tid = threadIdx.x;
  const int lane = tid & 63, w = tid >> 6;
  __shared__ float4    sdisp[256];        // 4 KB
  __shared__ _Float16  yt[64 * 256];      // 32 KB, row stride 512B
  __shared__ float     red[256];

  const int c = lane;
  float4 wc = fold1_chan(acc9, t, c, W1, g1, b1);
  f32x4 g0 = {0.f,0.f,0.f,0.f}, g1a = {0.f,0.f,0.f,0.f};
  f32x4 g2a = {0.f,0.f,0.f,0.f}, g3 = {0.f,0.f,0.f,0.f};
  float ysum = 0.f;
  const int frc = lane & 15, kg = lane >> 4;
  const int fsw = frc & 7;                // read-side row swizzle (row&7, rows≡frc mod 8)

  for (int rnd = 0; rnd < 8; ++rnd) {
    int smp = (chunk << 11) + (rnd << 8) + tid;
    size_t flat = ((size_t)(smp >> 15) << 18) + ((size_t)t << 15) + (smp & 32767);
    sdisp[tid] = ((const float4*)disp4)[flat];
    __syncthreads();
    // y1: thread does c=lane, samples [w*64, w*64+64)
    char* rowb = (char*)yt + c * 512;
    const int cs = c & 7;
#pragma unroll
    for (int u8 = 0; u8 < 8; ++u8) {
      half8 hv;
#pragma unroll
      for (int u = 0; u < 8; ++u) {
        float4 d = sdisp[(w << 6) + (u8 << 3) + u];
        float y = wc.x * d.x + wc.y * d.y + wc.z * d.z + wc.w;
        y = y > 0.f ? y : 0.f;
        ysum += y;
        hv[u] = (_Float16)y;
      }
      int g = (w << 3) + u8;              // granule 0..31 in row
      *(half8*)(rowb + (((g ^ cs)) << 4)) = hv;
    }
    __syncthreads();
#pragma unroll
    for (int ss = 0; ss < 8; ++ss) {
      int gg = (ss << 2) + kg;
      half8 fA = *(const half8*)((char*)yt + ((16 * w + frc) << 9) + ((gg ^ fsw) << 4));
      half8 f0 = *(const half8*)((char*)yt + ((frc) << 9)          + ((gg ^ fsw) << 4));
      half8 f1 = *(const half8*)((char*)yt + ((16 + frc) << 9)     + ((gg ^ fsw) << 4));
      half8 f2 = *(const half8*)((char*)yt + ((32 + frc) << 9)     + ((gg ^ fsw) << 4));
      half8 f3 = *(const half8*)((char*)yt + ((48 + frc) << 9)     + ((gg ^ fsw) << 4));
      g0  = __builtin_amdgcn_mfma_f32_16x16x32_f16(fA, f0, g0, 0, 0, 0);
      g1a = __builtin_amdgcn_mfma_f32_16x16x32_f16(fA, f1, g1a, 0, 0, 0);
      g2a = __builtin_amdgcn_mfma_f32_16x16x32_f16(fA, f2, g2a, 0, 0, 0);
      g3  = __builtin_amdgcn_mfma_f32_16x16x32_f16(fA, f3, g3, 0, 0, 0);
    }
    __syncthreads();
  }
  red[tid] = ysum;
  __syncthreads();
  if (tid < 64) {
    float v = red[tid] + red[tid + 64] + red[tid + 128] + red[tid + 192];
    atomicAdd(&sumy[t * 64 + tid], v);
  }
  float* Gp = G + t * 4096;
  const int rbase = 16 * w + (lane >> 4) * 4, cb = lane & 15;
#pragma unroll
  for (int r2 = 0; r2 < 4; ++r2) {
    atomicAdd(&Gp[(rbase + r2) * 64 + cb],      g0[r2]);
    atomicAdd(&Gp[(rbase + r2) * 64 + 16 + cb], g1a[r2]);
    atomicAdd(&Gp[(rbase + r2) * 64 + 32 + cb], g2a[r2]);
    atomicAdd(&Gp[(rbase + r2) * 64 + 48 + cb], g3[r2]);
  }
}

// ---------------------------------------------------------------- BN2 fold -> f16 W2'
__global__ __launch_bounds__(256) void fold2_kernel(const float* __restrict__ G,
    const float* __restrict__ sumy, const float* __restrict__ W2,
    const float* __restrict__ g2, const float* __restrict__ b2,
    _Float16* __restrict__ w2ph, float* __restrict__ beta2) {
  const int gidx = blockIdx.x * 256 + threadIdx.x;  // 0..1023
  const int t = gidx >> 7, c2 = gidx & 127;
  const float inv_n = 1.f / 65536.f;
  const float* w = W2 + c2 * 64;
  float wreg[64];
#pragma unroll
  for (int q = 0; q < 16; ++q) {
    float4 v = ((const float4*)w)[q];
    wreg[4 * q] = v.x; wreg[4 * q + 1] = v.y; wreg[4 * q + 2] = v.z; wreg[4 * q + 3] = v.w;
  }
  float mean2 = 0.f;
#pragma unroll
  for (int j = 0; j < 64; ++j) mean2 += wreg[j] * (sumy[t * 64 + j] * inv_n);
  const float* Gp = G + t * 4096;
  float E2 = 0.f;
  for (int i = 0; i < 64; ++i) {
    const float* gr = Gp + i * 64;
    float gw = 0.f;
#pragma unroll
    for (int j = 0; j < 64; j += 4) {
      float4 gv = *(const float4*)&gr[j];
      gw += gv.x * wreg[j] + gv.y * wreg[j + 1] + gv.z * wreg[j + 2] + gv.w * wreg[j + 3];
    }
    E2 += wreg[i] * gw;
  }
  E2 *= inv_n;
  float var = E2 - mean2 * mean2;
  float al = g2[c2] / sqrtf(var + 1e-5f);
  float be = b2[c2] - mean2 * al;
  beta2[t * 128 + c2] = be;
  _Float16* wo = w2ph + (size_t)(t * 128 + c2) * 64;
#pragma unroll
  for (int j = 0; j < 64; ++j) wo[j] = (_Float16)(al * wreg[j]);
}

// ---------------------------------------------------------------- final: f16 MFMA GEMM + k-max
__global__ __launch_bounds__(256) void final_mfma(
    const float* __restrict__ disp4, const float* __restrict__ acc9,
    const float* __restrict__ W1, const float* __restrict__ g1,
    const float* __restrict__ b1,
    const _Float16* __restrict__ w2ph, const float* __restrict__ beta2,
    float* __restrict__ outfeat) {
  const int bid = blockIdx.x;          // 1024 = bt(16) x mgrp(64)
  const int bt = bid >> 6, mg = bid & 63;
  const int t = bt & 7;
  const int tid = threadIdx.x;
  const int lane = tid & 63, w = tid >> 6;

  __shared__ float4    sdisp[512];     // 16 m x 32 k (8 KB)
  __shared__ _Float16  sy[512 * 64];   // swizzled y1 (64 KB)

  {
    const float4* src = (const float4*)disp4 + (((size_t)(bt << 10) + (mg << 4)) << 5);
    sdisp[tid] = src[tid];
    sdisp[tid + 256] = src[tid + 256];
  }
  const int c0 = (tid & 31) * 2;
  float4 w1a = fold1_chan(acc9, t, c0, W1, g1, b1);
  float4 w1b = fold1_chan(acc9, t, c0 + 1, W1, g1, b1);
  __syncthreads();

  {
    const int r0 = (tid >> 5) * 64;
    const int hg = c0 >> 3;
    const int cin = (c0 & 7) * 2;
#pragma unroll 4
    for (int rr = 0; rr < 64; ++rr) {
      int row = r0 + rr;
      float4 d = sdisp[row];
      float ya = fmaxf(w1a.x * d.x + w1a.y * d.y + w1a.z * d.z + w1a.w, 0.f);
      float yb = fmaxf(w1b.x * d.x + w1b.y * d.y + w1b.z * d.z + w1b.w, 0.f);
      _Float16* p = (_Float16*)((char*)sy + row * 128 + ((hg ^ (row & 7)) * 16) + cin);
      p[0] = (_Float16)ya;
      p[1] = (_Float16)yb;
    }
  }
  __syncthreads();

  const int col = lane & 15, kg = lane >> 4;
  for (int ct = 0; ct < 8; ++ct) {
    const _Float16* wb = w2ph + ((size_t)(t * 128 + ct * 16 + col)) * 64 + kg * 8;
    half8 bf0 = *(const half8*)wb;
    half8 bf1 = *(const half8*)(wb + 32);
    float b2v = beta2[t * 128 + ct * 16 + col];
#pragma unroll
    for (int mi = 0; mi < 4; ++mi) {
      float mx = -1e30f;
#pragma unroll
      for (int h = 0; h < 2; ++h) {
        int row = (8 * w + 2 * mi + h) * 16 + col;
        int rm = row & 7;
        const char* rb = (const char*)sy + row * 128;
        half8 a0 = *(const half8*)(rb + ((kg ^ rm) * 16));
        half8 a1 = *(const half8*)(rb + (((4 + kg) ^ rm) * 16));
        f32x4 acc = {0.f, 0.f, 0.f, 0.f};
        acc = __builtin_amdgcn_mfma_f32_16x16x32_f16(a0, bf0, acc, 0, 0, 0);
        acc = __builtin_amdgcn_mfma_f32_16x16x32_f16(a1, bf1, acc, 0, 0, 0);
        float z = fmaxf(fmaxf(acc[0], acc[1]), fmaxf(acc[2], acc[3]));
        mx = fmaxf(mx, z);
      }
      mx = fmaxf(mx, __shfl_xor(mx, 16));
      mx = fmaxf(mx, __shfl_xor(mx, 32));
      if (lane < 16) {
        float v = fmaxf(mx + b2v, 0.f);
        int m = (mg << 4) + 4 * w + mi;
        outfeat[((size_t)(bt * 128 + ct * 16 + lane)) * 1024 + m] = v;
      }
    }
  }
}

// ---------------------------------------------------------------- launch
extern "C" void kernel_launch(void* const* d_in, const int* in_sizes, int n_in,
                              void* d_out, int out_size, void* d_ws, size_t ws_size,
                              hipStream_t stream) {
  const float* xyzs = (const float*)d_in[0];
  const float* W1   = (const float*)d_in[1];
  const float* g1   = (const float*)d_in[2];
  const float* b1   = (const float*)d_in[3];
  const float* W2   = (const float*)d_in[4];
  const float* g2   = (const float*)d_in[5];
  const float* b2   = (const float*)d_in[6];
  float* out = (float*)d_out;
  float* ws  = (float*)d_ws;

  float*     disp4 = ws;               // 2,097,152 floats (B,T,M,K,4)
  float*     acc   = ws + 2097152;     // 72
  float*     sumy  = ws + 2097224;     // 512
  float*     G     = ws + 2097736;     // 32768 (acc..G contiguous for one memset)
  _Float16*  w2ph  = (_Float16*)(ws + 2130504);  // 65536 halves
  float*     beta2 = ws + 2163272;     // 1024

  hipMemsetAsync(acc, 0, (72 + 512 + 32768) * sizeof(float), stream);
  fps_kernel  <<<256,  512, 0, stream>>>(xyzs, out);
  ball_stats  <<<4096, 256, 0, stream>>>(xyzs, out, disp4, acc);
  gram_mfma   <<<256,  256, 0, stream>>>(disp4, acc, W1, g1, b1, sumy, G);
  fold2_kernel<<<4,    256, 0, stream>>>(G, sumy, W2, g2, b2, w2ph, beta2);
  final_mfma  <<<1024, 256, 0, stream>>>(disp4, acc, W1, g1, b1, w2ph, beta2, out + 49152);
}